// Round 1
// baseline (48340.198 us; speedup 1.0000x reference)
//
#include <hip/hip_runtime.h>
#include <math.h>

#define BS 128
#define L 512
#define ENC 512
#define DEC 1024
#define ATTN 512
#define EMB 256
#define VOCAB 128
#define TMAX 128
#define KCAT 1792  // EMB+ENC+DEC
#define G4 4096    // 4*DEC

// ---- workspace layout (float offsets) ----
#define OFF_WE     0ull                       // [BS][ATTN][L]   33554432
#define OFF_WG     33554432ull                // [G4][KCAT]       7340032
#define OFF_BG     40894464ull                // [G4]                4096
#define OFF_WOUTT  40898560ull                // [DEC][VOCAB]      131072
#define OFF_H      41029632ull                // [BS][DEC]         131072
#define OFF_HT     41160704ull                // [DEC][BS]         131072
#define OFF_C      41291776ull                // [BS][DEC]         131072
#define OFF_WDEC   41422848ull                // [BS][ATTN]         65536
#define OFF_SC     41488384ull                // [BS][L]            65536
#define OFF_XCAT   41553920ull                // [BS][KCAT]        229376
#define OFF_GATES  41783296ull                // [2][BS][G4]      1048576
// end: 42831872 floats = 171.3 MB

// ---------------- one-time prep: W_gate concat, bias sum, W_out^T ----------------
__global__ void k_prep(const float* __restrict__ W_ih, const float* __restrict__ W_hh,
                       const float* __restrict__ b_ih, const float* __restrict__ b_hh,
                       const float* __restrict__ W_out,
                       float* __restrict__ Wg, float* __restrict__ bg, float* __restrict__ WoutT) {
    long i = (long)blockIdx.x * 256 + threadIdx.x;
    if (i < (long)G4 * KCAT) {
        int r = (int)(i / KCAT), cidx = (int)(i % KCAT);
        Wg[i] = (cidx < EMB + ENC) ? W_ih[(long)r * (EMB + ENC) + cidx]
                                   : W_hh[(long)r * DEC + (cidx - (EMB + ENC))];
        return;
    }
    long j = i - (long)G4 * KCAT;
    if (j < G4) { bg[j] = b_ih[j] + b_hh[j]; return; }
    long m = j - G4;
    if (m < (long)DEC * VOCAB) {
        int k = (int)(m / VOCAB), v = (int)(m % VOCAB);
        WoutT[m] = W_out[(long)v * DEC + k];
    }
}

// ---------------- one-time init: h=c=hT=0, Xcat=[emb(SOS) | 0 | 0] ----------------
__global__ void k_init(const float* __restrict__ emb_table, float* __restrict__ h,
                       float* __restrict__ hT, float* __restrict__ c, float* __restrict__ Xcat) {
    long i = (long)blockIdx.x * 256 + threadIdx.x;
    if (i < BS * DEC) { h[i] = 0.f; hT[i] = 0.f; c[i] = 0.f; return; }
    long j = i - BS * DEC;
    if (j < (long)BS * KCAT) {
        int cdx = (int)(j % KCAT);
        Xcat[j] = (cdx < EMB) ? emb_table[cdx] : 0.f;  // SOS = row 0
    }
}

// ---------------- weighted_enc[b,a,l] = sum_e W_enc[a,e]*enc[b,e,l] + b_enc[a] ----------------
__global__ __launch_bounds__(256) void k_wenc(const float* __restrict__ W_enc,
                                              const float* __restrict__ b_enc,
                                              const float* __restrict__ enc_out,
                                              float* __restrict__ we) {
    __shared__ float As[16][68];
    __shared__ float Bs[16][68];
    int b = blockIdx.z;
    int a0 = blockIdx.y * 64;
    int l0 = blockIdx.x * 64;
    int t = threadIdx.x;
    int ty = t >> 4, tx = t & 15;
    float acc[4][4] = {};
    for (int e0 = 0; e0 < ENC; e0 += 16) {
        {
            int ar = t >> 2;
            int kg = (t & 3) << 2;
            float4 w4 = *(const float4*)&W_enc[(size_t)(a0 + ar) * ENC + e0 + kg];
            As[kg + 0][ar] = w4.x; As[kg + 1][ar] = w4.y; As[kg + 2][ar] = w4.z; As[kg + 3][ar] = w4.w;
            int er = t >> 4;
            int lg = (t & 15) << 2;
            float4 x4 = *(const float4*)&enc_out[((size_t)b * ENC + e0 + er) * L + l0 + lg];
            *(float4*)&Bs[er][lg] = x4;
        }
        __syncthreads();
        #pragma unroll
        for (int kk = 0; kk < 16; kk++) {
            float4 a4 = *(const float4*)&As[kk][ty * 4];
            float4 x4 = *(const float4*)&Bs[kk][tx * 4];
            float av[4] = {a4.x, a4.y, a4.z, a4.w};
            float xv[4] = {x4.x, x4.y, x4.z, x4.w};
            #pragma unroll
            for (int i = 0; i < 4; i++)
                #pragma unroll
                for (int j = 0; j < 4; j++) acc[i][j] += av[i] * xv[j];
        }
        __syncthreads();
    }
    #pragma unroll
    for (int i = 0; i < 4; i++) {
        float be = b_enc[a0 + ty * 4 + i];
        float4 o = {acc[i][0] + be, acc[i][1] + be, acc[i][2] + be, acc[i][3] + be};
        *(float4*)&we[((size_t)b * ATTN + a0 + ty * 4 + i) * L + l0 + tx * 4] = o;
    }
}

// ---------------- wdec[b,a] = h[b,:] . W_dec[a,:] + b_dec[a] ----------------
__global__ __launch_bounds__(256) void k_wdec(const float* __restrict__ W_dec,
                                              const float* __restrict__ b_dec,
                                              const float* __restrict__ hT,
                                              float* __restrict__ wdec) {
    __shared__ float Ws[4][DEC];
    __shared__ float red[256][4];
    int a0 = blockIdx.x * 4;
    int t = threadIdx.x;
    for (int i = t; i < 4 * DEC; i += 256) {
        int r = i >> 10, k = i & 1023;
        Ws[r][k] = W_dec[(size_t)(a0 + r) * DEC + k];
    }
    __syncthreads();
    int b = t & 127, kh = t >> 7;
    float acc[4] = {};
    for (int k = kh * 512; k < kh * 512 + 512; k++) {
        float hv = hT[(size_t)k * BS + b];
        #pragma unroll
        for (int r = 0; r < 4; r++) acc[r] += Ws[r][k] * hv;
    }
    #pragma unroll
    for (int r = 0; r < 4; r++) red[t][r] = acc[r];
    __syncthreads();
    if (t < 128) {
        #pragma unroll
        for (int r = 0; r < 4; r++)
            wdec[(size_t)t * ATTN + a0 + r] = red[t][r] + red[t + 128][r] + b_dec[a0 + r];
    }
}

// ---------------- scores[b,l] = sum_a v_e[a]*tanh(we[b,a,l]+wdec[b,a]) + b_e ----------------
__global__ __launch_bounds__(256) void k_scores(const float* __restrict__ we,
                                                const float* __restrict__ wdec,
                                                const float* __restrict__ v_e,
                                                const float* __restrict__ b_e,
                                                float* __restrict__ scores) {
    __shared__ float wd[ATTN];
    __shared__ float ve[ATTN];
    __shared__ float red[128];
    int b = blockIdx.x >> 2;
    int l0 = (blockIdx.x & 3) * 128;
    int t = threadIdx.x;
    wd[t] = wdec[(size_t)b * ATTN + t];
    wd[t + 256] = wdec[(size_t)b * ATTN + t + 256];
    ve[t] = v_e[t];
    ve[t + 256] = v_e[t + 256];
    __syncthreads();
    int l = l0 + (t & 127);
    int ah = t >> 7;
    const float* p = we + ((size_t)b * ATTN + ah * 256) * L + l;
    float acc = 0.f;
    #pragma unroll 4
    for (int a = 0; a < 256; a++) {
        float x = p[(size_t)a * L] + wd[ah * 256 + a];
        acc += ve[ah * 256 + a] * tanhf(x);
    }
    if (ah == 1) red[t & 127] = acc;
    __syncthreads();
    if (ah == 0) scores[(size_t)b * L + l] = acc + red[t] + b_e[0];
}

// ---------------- softmax over L, write alphas into d_out attn slot ----------------
__global__ __launch_bounds__(256) void k_softmax(const float* __restrict__ scores,
                                                 float* __restrict__ attn_out, int t_step) {
    __shared__ float red[256];
    int b = blockIdx.x;
    int t = threadIdx.x;
    float v0 = scores[(size_t)b * L + t], v1 = scores[(size_t)b * L + t + 256];
    red[t] = fmaxf(v0, v1);
    __syncthreads();
    for (int s = 128; s > 0; s >>= 1) { if (t < s) red[t] = fmaxf(red[t], red[t + s]); __syncthreads(); }
    float m = red[0];
    __syncthreads();
    float e0 = __expf(v0 - m), e1 = __expf(v1 - m);
    // use precise expf to stay close to reference
    e0 = expf(v0 - m); e1 = expf(v1 - m);
    red[t] = e0 + e1;
    __syncthreads();
    for (int s = 128; s > 0; s >>= 1) { if (t < s) red[t] += red[t + s]; __syncthreads(); }
    float inv = 1.f / red[0];
    float* dst = attn_out + ((size_t)b * TMAX + t_step) * L;
    dst[t] = e0 * inv;
    dst[t + 256] = e1 * inv;
}

// ---------------- context[b,e] = sum_l enc[b,e,l]*alpha[b,l] -> Xcat[b, EMB+e] ----------------
__global__ __launch_bounds__(256) void k_context(const float* __restrict__ enc_out,
                                                 const float* __restrict__ attn_out,
                                                 float* __restrict__ Xcat, int t_step) {
    int w = blockIdx.x * 4 + (threadIdx.x >> 6);
    int lane = threadIdx.x & 63;
    int b = w >> 9;
    int e = w & 511;
    const float* ep = enc_out + ((size_t)b * ENC + e) * L;
    const float* ap = attn_out + ((size_t)b * TMAX + t_step) * L;
    float acc = 0.f;
    #pragma unroll
    for (int i = 0; i < 8; i++) acc += ep[lane + 64 * i] * ap[lane + 64 * i];
    for (int s = 32; s; s >>= 1) acc += __shfl_down(acc, s, 64);
    if (lane == 0) Xcat[(size_t)b * KCAT + EMB + e] = acc;
}

// ---------------- gates2[ks][b][m] = sum_{k in split} Wg[m,k]*Xcat[b,k] ----------------
__global__ __launch_bounds__(256) void k_gates(const float* __restrict__ Wg,
                                               const float* __restrict__ Xcat,
                                               float* __restrict__ gates2) {
    __shared__ float As[16][68];
    __shared__ float Xs[16][68];
    int m0 = blockIdx.x * 64;
    int b0 = blockIdx.y * 64;
    int ksp = blockIdx.z;
    int t = threadIdx.x;
    int ty = t >> 4, tx = t & 15;
    float acc[4][4] = {};
    for (int k0 = ksp * 896; k0 < ksp * 896 + 896; k0 += 16) {
        int r = t >> 2, kg = (t & 3) << 2;
        float4 w4 = *(const float4*)&Wg[(size_t)(m0 + r) * KCAT + k0 + kg];
        float4 x4 = *(const float4*)&Xcat[(size_t)(b0 + r) * KCAT + k0 + kg];
        As[kg + 0][r] = w4.x; As[kg + 1][r] = w4.y; As[kg + 2][r] = w4.z; As[kg + 3][r] = w4.w;
        Xs[kg + 0][r] = x4.x; Xs[kg + 1][r] = x4.y; Xs[kg + 2][r] = x4.z; Xs[kg + 3][r] = x4.w;
        __syncthreads();
        #pragma unroll
        for (int kk = 0; kk < 16; kk++) {
            float4 a4 = *(const float4*)&As[kk][ty * 4];
            float4 x4i = *(const float4*)&Xs[kk][tx * 4];
            float av[4] = {a4.x, a4.y, a4.z, a4.w};
            float xv[4] = {x4i.x, x4i.y, x4i.z, x4i.w};
            #pragma unroll
            for (int i = 0; i < 4; i++)
                #pragma unroll
                for (int j = 0; j < 4; j++) acc[i][j] += av[i] * xv[j];
        }
        __syncthreads();
    }
    float* gp = gates2 + (size_t)ksp * BS * G4;
    #pragma unroll
    for (int j = 0; j < 4; j++) {
        float4 o = {acc[0][j], acc[1][j], acc[2][j], acc[3][j]};
        *(float4*)&gp[(size_t)(b0 + tx * 4 + j) * G4 + m0 + ty * 4] = o;
    }
}

// ---------------- LSTM cell; writes h, hT, c, and h into Xcat ----------------
__global__ __launch_bounds__(256) void k_cell(const float* __restrict__ gates2,
                                              const float* __restrict__ bg,
                                              float* __restrict__ h, float* __restrict__ hT,
                                              float* __restrict__ c, float* __restrict__ Xcat) {
    int i = blockIdx.x * 256 + threadIdx.x;  // < BS*DEC
    int b = i >> 10, d = i & 1023;
    const float* g0 = gates2 + (size_t)b * G4;
    const float* g1 = gates2 + (size_t)BS * G4 + (size_t)b * G4;
    float gi = g0[d]        + g1[d]        + bg[d];
    float gf = g0[d + 1024] + g1[d + 1024] + bg[d + 1024];
    float gg = g0[d + 2048] + g1[d + 2048] + bg[d + 2048];
    float go = g0[d + 3072] + g1[d + 3072] + bg[d + 3072];
    float fi = 1.f / (1.f + expf(-gi));
    float ff = 1.f / (1.f + expf(-gf));
    float fg = tanhf(gg);
    float fo = 1.f / (1.f + expf(-go));
    float cn = ff * c[i] + fi * fg;
    float hn = fo * tanhf(cn);
    c[i] = cn;
    h[i] = hn;
    hT[(size_t)d * BS + b] = hn;
    Xcat[(size_t)b * KCAT + EMB + ENC + d] = hn;
}

// ---------------- logits -> log_softmax -> argmax -> emb write ----------------
__global__ __launch_bounds__(128) void k_out(const float* __restrict__ WoutT,
                                             const float* __restrict__ b_out,
                                             const float* __restrict__ h,
                                             const float* __restrict__ emb_table,
                                             float* __restrict__ logp_out,
                                             float* __restrict__ preds_out,
                                             float* __restrict__ Xcat, int t_step) {
    __shared__ float hs[DEC];
    __shared__ float rv[128];
    __shared__ int ri[128];
    int b = blockIdx.x;
    int v = threadIdx.x;
    for (int k = v; k < DEC; k += 128) hs[k] = h[(size_t)b * DEC + k];
    __syncthreads();
    float acc = b_out[v];
    #pragma unroll 8
    for (int k = 0; k < DEC; k++) acc += WoutT[(size_t)k * VOCAB + v] * hs[k];
    rv[v] = acc; ri[v] = v;
    __syncthreads();
    for (int s = 64; s; s >>= 1) {
        if (v < s) {
            float ov = rv[v + s]; int oi = ri[v + s];
            if (ov > rv[v] || (ov == rv[v] && oi < ri[v])) { rv[v] = ov; ri[v] = oi; }
        }
        __syncthreads();
    }
    float m = rv[0]; int am = ri[0];
    __syncthreads();
    rv[v] = expf(acc - m);
    __syncthreads();
    for (int s = 64; s; s >>= 1) { if (v < s) rv[v] += rv[v + s]; __syncthreads(); }
    float lse = logf(rv[0]);
    logp_out[((size_t)b * TMAX + t_step) * VOCAB + v] = acc - m - lse;
    if (v == 0) preds_out[(size_t)b * TMAX + t_step] = (float)am;
    #pragma unroll
    for (int j = 0; j < 2; j++)
        Xcat[(size_t)b * KCAT + v + 128 * j] = emb_table[(size_t)am * EMB + v + 128 * j];
}

extern "C" void kernel_launch(void* const* d_in, const int* in_sizes, int n_in,
                              void* d_out, int out_size, void* d_ws, size_t ws_size,
                              hipStream_t stream) {
    const float* enc_out = (const float*)d_in[0];
    const float* W_enc   = (const float*)d_in[1];
    const float* b_enc   = (const float*)d_in[2];
    const float* W_dec   = (const float*)d_in[3];
    const float* b_dec   = (const float*)d_in[4];
    const float* v_e     = (const float*)d_in[5];
    const float* b_e     = (const float*)d_in[6];
    const float* emb     = (const float*)d_in[7];
    const float* W_ih    = (const float*)d_in[8];
    const float* W_hh    = (const float*)d_in[9];
    const float* b_ih    = (const float*)d_in[10];
    const float* b_hh    = (const float*)d_in[11];
    const float* W_out   = (const float*)d_in[12];
    const float* b_out   = (const float*)d_in[13];

    float* ws    = (float*)d_ws;
    float* we    = ws + OFF_WE;
    float* Wg    = ws + OFF_WG;
    float* bg    = ws + OFF_BG;
    float* WoutT = ws + OFF_WOUTT;
    float* h     = ws + OFF_H;
    float* hT    = ws + OFF_HT;
    float* c     = ws + OFF_C;
    float* wdec  = ws + OFF_WDEC;
    float* sc    = ws + OFF_SC;
    float* Xcat  = ws + OFF_XCAT;
    float* gates2= ws + OFF_GATES;

    float* logp_out  = (float*)d_out;
    float* preds_out = logp_out + (size_t)BS * TMAX * VOCAB;
    float* attn_out  = preds_out + (size_t)BS * TMAX;

    {
        long n = (long)G4 * KCAT + G4 + (long)DEC * VOCAB;
        k_prep<<<(int)((n + 255) / 256), 256, 0, stream>>>(W_ih, W_hh, b_ih, b_hh, W_out, Wg, bg, WoutT);
    }
    {
        long n = (long)BS * DEC + (long)BS * KCAT;
        k_init<<<(int)((n + 255) / 256), 256, 0, stream>>>(emb, h, hT, c, Xcat);
    }
    k_wenc<<<dim3(8, 8, 128), 256, 0, stream>>>(W_enc, b_enc, enc_out, we);

    for (int t = 0; t < TMAX; t++) {
        k_wdec<<<128, 256, 0, stream>>>(W_dec, b_dec, hT, wdec);
        k_scores<<<512, 256, 0, stream>>>(we, wdec, v_e, b_e, sc);
        k_softmax<<<128, 256, 0, stream>>>(sc, attn_out, t);
        k_context<<<16384, 256, 0, stream>>>(enc_out, attn_out, Xcat, t);
        k_gates<<<dim3(64, 2, 2), 256, 0, stream>>>(Wg, Xcat, gates2);
        k_cell<<<512, 256, 0, stream>>>(gates2, bg, h, hT, c, Xcat);
        k_out<<<128, 128, 0, stream>>>(WoutT, b_out, h, emb, logp_out, preds_out, Xcat, t);
    }
}

// Round 4
// 44572.351 us; speedup vs baseline: 1.0845x; 1.0845x over previous
//
#include <hip/hip_runtime.h>
#include <math.h>

#define BS 128
#define L 512
#define ENC 512
#define DEC 1024
#define ATTN 512
#define EMB 256
#define VOCAB 128
#define TMAX 128
#define KCAT 1792  // EMB+ENC+DEC
#define G4 4096    // 4*DEC

// ---- workspace layout (float offsets) ----
#define OFF_WE     0ull                       // [BS][ATTN][L]   33554432
#define OFF_WGR    33554432ull                // [G4][KCAT] d-major  7340032
#define OFF_BGR    40894464ull                // [G4] d-major         4096
#define OFF_WOUTT  40898560ull                // [DEC][VOCAB]       131072
#define OFF_H      41029632ull                // [BS][DEC]          131072
#define OFF_HT     41160704ull                // [DEC][BS]          131072
#define OFF_C      41291776ull                // [BS][DEC]          131072
#define OFF_WDEC   41422848ull                // [BS][ATTN]          65536
#define OFF_SC     41488384ull                // [BS][L]             65536
#define OFF_XCAT   41553920ull                // [BS][KCAT]         229376
// end: 41783296 floats = 167.1 MB

// ---------------- one-time prep: d-major W_gate concat, bias sum, W_out^T ----------------
__global__ void k_prep(const float* __restrict__ W_ih, const float* __restrict__ W_hh,
                       const float* __restrict__ b_ih, const float* __restrict__ b_hh,
                       const float* __restrict__ W_out,
                       float* __restrict__ Wgr, float* __restrict__ bgr, float* __restrict__ WoutT) {
    long i = (long)blockIdx.x * 256 + threadIdx.x;
    if (i < (long)G4 * KCAT) {
        int mp = (int)(i / KCAT), k = (int)(i % KCAT);
        int d = mp >> 2, g = mp & 3;
        int r = g * DEC + d;  // original gate-major row
        Wgr[i] = (k < EMB + ENC) ? W_ih[(long)r * (EMB + ENC) + k]
                                 : W_hh[(long)r * DEC + (k - (EMB + ENC))];
        return;
    }
    long j = i - (long)G4 * KCAT;
    if (j < G4) {
        int d = (int)(j >> 2), g = (int)(j & 3);
        int r = g * DEC + d;
        bgr[j] = b_ih[r] + b_hh[r];
        return;
    }
    long m = j - G4;
    if (m < (long)DEC * VOCAB) {
        int k = (int)(m / VOCAB), v = (int)(m % VOCAB);
        WoutT[m] = W_out[(long)v * DEC + k];
    }
}

// ---------------- one-time init: h=c=hT=0, Xcat=[emb(SOS) | 0 | 0] ----------------
__global__ void k_init(const float* __restrict__ emb_table, float* __restrict__ h,
                       float* __restrict__ hT, float* __restrict__ c, float* __restrict__ Xcat) {
    long i = (long)blockIdx.x * 256 + threadIdx.x;
    if (i < BS * DEC) { h[i] = 0.f; hT[i] = 0.f; c[i] = 0.f; return; }
    long j = i - BS * DEC;
    if (j < (long)BS * KCAT) {
        int cdx = (int)(j % KCAT);
        Xcat[j] = (cdx < EMB) ? emb_table[cdx] : 0.f;  // SOS = row 0
    }
}

// ---------------- weighted_enc[b,a,l] = sum_e W_enc[a,e]*enc[b,e,l] + b_enc[a] ----------------
__global__ __launch_bounds__(256) void k_wenc(const float* __restrict__ W_enc,
                                              const float* __restrict__ b_enc,
                                              const float* __restrict__ enc_out,
                                              float* __restrict__ we) {
    __shared__ float As[16][68];
    __shared__ float Bs[16][68];
    int b = blockIdx.z;
    int a0 = blockIdx.y * 64;
    int l0 = blockIdx.x * 64;
    int t = threadIdx.x;
    int ty = t >> 4, tx = t & 15;
    float acc[4][4] = {};
    for (int e0 = 0; e0 < ENC; e0 += 16) {
        {
            int ar = t >> 2;
            int kg = (t & 3) << 2;
            float4 w4 = *(const float4*)&W_enc[(size_t)(a0 + ar) * ENC + e0 + kg];
            As[kg + 0][ar] = w4.x; As[kg + 1][ar] = w4.y; As[kg + 2][ar] = w4.z; As[kg + 3][ar] = w4.w;
            int er = t >> 4;
            int lg = (t & 15) << 2;
            float4 x4 = *(const float4*)&enc_out[((size_t)b * ENC + e0 + er) * L + l0 + lg];
            *(float4*)&Bs[er][lg] = x4;
        }
        __syncthreads();
        #pragma unroll
        for (int kk = 0; kk < 16; kk++) {
            float4 a4 = *(const float4*)&As[kk][ty * 4];
            float4 x4 = *(const float4*)&Bs[kk][tx * 4];
            float av[4] = {a4.x, a4.y, a4.z, a4.w};
            float xv[4] = {x4.x, x4.y, x4.z, x4.w};
            #pragma unroll
            for (int i = 0; i < 4; i++)
                #pragma unroll
                for (int j = 0; j < 4; j++) acc[i][j] += av[i] * xv[j];
        }
        __syncthreads();
    }
    #pragma unroll
    for (int i = 0; i < 4; i++) {
        float be = b_enc[a0 + ty * 4 + i];
        float4 o = {acc[i][0] + be, acc[i][1] + be, acc[i][2] + be, acc[i][3] + be};
        *(float4*)&we[((size_t)b * ATTN + a0 + ty * 4 + i) * L + l0 + tx * 4] = o;
    }
}

// ---------------- wdec[b,a] = h[b,:] . W_dec[a,:] + b_dec[a]  (round-1 exact) ----------------
__global__ __launch_bounds__(256) void k_wdec(const float* __restrict__ W_dec,
                                              const float* __restrict__ b_dec,
                                              const float* __restrict__ hT,
                                              float* __restrict__ wdec) {
    __shared__ float Ws[4][DEC];
    __shared__ float red[256][4];
    int a0 = blockIdx.x * 4;
    int t = threadIdx.x;
    for (int i = t; i < 4 * DEC; i += 256) {
        int r = i >> 10, k = i & 1023;
        Ws[r][k] = W_dec[(size_t)(a0 + r) * DEC + k];
    }
    __syncthreads();
    int b = t & 127, kh = t >> 7;
    float acc[4] = {};
    #pragma unroll 8
    for (int k = kh * 512; k < kh * 512 + 512; k++) {
        float hv = hT[(size_t)k * BS + b];
        #pragma unroll
        for (int r = 0; r < 4; r++) acc[r] += Ws[r][k] * hv;
    }
    #pragma unroll
    for (int r = 0; r < 4; r++) red[t][r] = acc[r];
    __syncthreads();
    if (t < 128) {
        #pragma unroll
        for (int r = 0; r < 4; r++)
            wdec[(size_t)t * ATTN + a0 + r] = red[t][r] + red[t + 128][r] + b_dec[a0 + r];
    }
}

// ---------------- scores[b,l] = sum_a v_e[a]*tanh(we[b,a,l]+wdec[b,a]) + b_e (round-1 exact) ----------------
__global__ __launch_bounds__(256) void k_scores(const float* __restrict__ we,
                                                const float* __restrict__ wdec,
                                                const float* __restrict__ v_e,
                                                const float* __restrict__ b_e,
                                                float* __restrict__ scores) {
    __shared__ float wd[ATTN];
    __shared__ float ve[ATTN];
    __shared__ float red[128];
    int b = blockIdx.x >> 2;
    int l0 = (blockIdx.x & 3) * 128;
    int t = threadIdx.x;
    wd[t] = wdec[(size_t)b * ATTN + t];
    wd[t + 256] = wdec[(size_t)b * ATTN + t + 256];
    ve[t] = v_e[t];
    ve[t + 256] = v_e[t + 256];
    __syncthreads();
    int l = l0 + (t & 127);
    int ah = t >> 7;
    const float* p = we + ((size_t)b * ATTN + ah * 256) * L + l;
    float acc = 0.f;
    #pragma unroll 8
    for (int a = 0; a < 256; a++) {
        float x = p[(size_t)a * L] + wd[ah * 256 + a];
        acc += ve[ah * 256 + a] * tanhf(x);
    }
    if (ah == 1) red[t & 127] = acc;
    __syncthreads();
    if (ah == 0) scores[(size_t)b * L + l] = acc + red[t] + b_e[0];
}

// ---------------- fused softmax + context (bit-exact round-1 order) ----------------
__global__ __launch_bounds__(256) void k_smctx(const float* __restrict__ scores,
                                               const float* __restrict__ enc_out,
                                               float* __restrict__ attn_out,
                                               float* __restrict__ Xcat, int t_step) {
    __shared__ float al[L];
    __shared__ float red[256];
    int b = blockIdx.x >> 2, ec = blockIdx.x & 3;
    int t = threadIdx.x;
    // softmax: identical tree to round-1 k_softmax
    float v0 = scores[(size_t)b * L + t], v1 = scores[(size_t)b * L + t + 256];
    red[t] = fmaxf(v0, v1);
    __syncthreads();
    for (int s = 128; s; s >>= 1) { if (t < s) red[t] = fmaxf(red[t], red[t + s]); __syncthreads(); }
    float m = red[0];
    __syncthreads();
    float e0 = expf(v0 - m), e1 = expf(v1 - m);
    red[t] = e0 + e1;
    __syncthreads();
    for (int s = 128; s; s >>= 1) { if (t < s) red[t] += red[t + s]; __syncthreads(); }
    float inv = 1.f / red[0];
    al[t] = e0 * inv; al[t + 256] = e1 * inv;
    __syncthreads();
    if (ec == 0) {
        float* dst = attn_out + ((size_t)b * TMAX + t_step) * L;
        dst[t] = al[t]; dst[t + 256] = al[t + 256];
    }
    // context: identical per-e strided sum + shfl_down tree as round-1 k_context
    int w = t >> 6, lane = t & 63;
    for (int ei = 0; ei < 32; ei++) {
        int e = ec * 128 + w * 32 + ei;
        const float* ep = enc_out + ((size_t)b * ENC + e) * L;
        float acc = 0.f;
        #pragma unroll
        for (int i = 0; i < 8; i++) acc += ep[lane + 64 * i] * al[lane + 64 * i];
        for (int s = 32; s; s >>= 1) acc += __shfl_down(acc, s, 64);
        if (lane == 0) Xcat[(size_t)b * KCAT + EMB + e] = acc;
    }
}

// ---------------- gates GEMM (d-major) + LSTM cell; NO Xcat write (race-free) ----------------
__global__ __launch_bounds__(256) void k_gates_cell(const float* __restrict__ Wgr,
                                                    const float* __restrict__ bgr,
                                                    const float* __restrict__ Xcat,
                                                    float* __restrict__ h, float* __restrict__ hT,
                                                    float* __restrict__ c) {
    __shared__ float As[16][68];  // [k][m'] 64 rows
    __shared__ float Xs[16][36];  // [k][b]  32 cols
    int d0 = blockIdx.x * 16;
    int b0 = blockIdx.y * 32;
    int t = threadIdx.x, ty = t >> 4, tx = t & 15;
    float accA[4][2] = {};
    float accB[4][2] = {};
    for (int k0 = 0; k0 < KCAT; k0 += 16) {
        int r = t >> 2, kg = (t & 3) << 2;
        float4 w4 = *(const float4*)&Wgr[(size_t)(d0 * 4 + r) * KCAT + k0 + kg];
        As[kg + 0][r] = w4.x; As[kg + 1][r] = w4.y; As[kg + 2][r] = w4.z; As[kg + 3][r] = w4.w;
        if (t < 128) {
            int br = t >> 2;
            float4 x4 = *(const float4*)&Xcat[(size_t)(b0 + br) * KCAT + k0 + kg];
            Xs[kg + 0][br] = x4.x; Xs[kg + 1][br] = x4.y; Xs[kg + 2][br] = x4.z; Xs[kg + 3][br] = x4.w;
        }
        __syncthreads();
        if (k0 < 896) {
            #pragma unroll
            for (int kk = 0; kk < 16; kk++) {
                float4 a4 = *(const float4*)&As[kk][ty * 4];
                float xb0 = Xs[kk][tx * 2], xb1 = Xs[kk][tx * 2 + 1];
                accA[0][0] += a4.x * xb0; accA[0][1] += a4.x * xb1;
                accA[1][0] += a4.y * xb0; accA[1][1] += a4.y * xb1;
                accA[2][0] += a4.z * xb0; accA[2][1] += a4.z * xb1;
                accA[3][0] += a4.w * xb0; accA[3][1] += a4.w * xb1;
            }
        } else {
            #pragma unroll
            for (int kk = 0; kk < 16; kk++) {
                float4 a4 = *(const float4*)&As[kk][ty * 4];
                float xb0 = Xs[kk][tx * 2], xb1 = Xs[kk][tx * 2 + 1];
                accB[0][0] += a4.x * xb0; accB[0][1] += a4.x * xb1;
                accB[1][0] += a4.y * xb0; accB[1][1] += a4.y * xb1;
                accB[2][0] += a4.z * xb0; accB[2][1] += a4.z * xb1;
                accB[3][0] += a4.w * xb0; accB[3][1] += a4.w * xb1;
            }
        }
        __syncthreads();
    }
    int d = d0 + ty;
    float4 bb = *(const float4*)&bgr[(size_t)d * 4];
    #pragma unroll
    for (int j = 0; j < 2; j++) {
        int b = b0 + tx * 2 + j;
        float gi = accA[0][j] + accB[0][j] + bb.x;
        float gf = accA[1][j] + accB[1][j] + bb.y;
        float gg = accA[2][j] + accB[2][j] + bb.z;
        float go = accA[3][j] + accB[3][j] + bb.w;
        float fi = 1.f / (1.f + expf(-gi));
        float ff = 1.f / (1.f + expf(-gf));
        float fg = tanhf(gg);
        float fo = 1.f / (1.f + expf(-go));
        size_t ix = (size_t)b * DEC + d;
        float cn = ff * c[ix] + fi * fg;
        float hn = fo * tanhf(cn);
        c[ix] = cn;
        h[ix] = hn;
        hT[(size_t)d * BS + b] = hn;
    }
}

// ---------------- logits -> log_softmax -> argmax -> emb + h write into Xcat ----------------
__global__ __launch_bounds__(128) void k_out(const float* __restrict__ WoutT,
                                             const float* __restrict__ b_out,
                                             const float* __restrict__ h,
                                             const float* __restrict__ emb_table,
                                             float* __restrict__ logp_out,
                                             float* __restrict__ preds_out,
                                             float* __restrict__ Xcat, int t_step) {
    __shared__ float hs[DEC];
    __shared__ float rv[128];
    __shared__ int ri[128];
    int b = blockIdx.x;
    int v = threadIdx.x;
    for (int k = v; k < DEC; k += 128) hs[k] = h[(size_t)b * DEC + k];
    __syncthreads();
    float acc = b_out[v];
    #pragma unroll 8
    for (int k = 0; k < DEC; k++) acc += WoutT[(size_t)k * VOCAB + v] * hs[k];
    rv[v] = acc; ri[v] = v;
    __syncthreads();
    for (int s = 64; s; s >>= 1) {
        if (v < s) {
            float ov = rv[v + s]; int oi = ri[v + s];
            if (ov > rv[v] || (ov == rv[v] && oi < ri[v])) { rv[v] = ov; ri[v] = oi; }
        }
        __syncthreads();
    }
    float m = rv[0]; int am = ri[0];
    __syncthreads();
    rv[v] = expf(acc - m);
    __syncthreads();
    for (int s = 64; s; s >>= 1) { if (v < s) rv[v] += rv[v + s]; __syncthreads(); }
    float lse = logf(rv[0]);
    logp_out[((size_t)b * TMAX + t_step) * VOCAB + v] = acc - m - lse;
    if (v == 0) preds_out[(size_t)b * TMAX + t_step] = (float)am;
    #pragma unroll
    for (int j = 0; j < 2; j++)
        Xcat[(size_t)b * KCAT + v + 128 * j] = emb_table[(size_t)am * EMB + v + 128 * j];
    // h -> Xcat h-part for next step's gates GEMM (race-free: k_gates_cell has completed)
    #pragma unroll
    for (int k = v; k < DEC; k += 128)
        Xcat[(size_t)b * KCAT + EMB + ENC + k] = hs[k];
}

extern "C" void kernel_launch(void* const* d_in, const int* in_sizes, int n_in,
                              void* d_out, int out_size, void* d_ws, size_t ws_size,
                              hipStream_t stream) {
    const float* enc_out = (const float*)d_in[0];
    const float* W_enc   = (const float*)d_in[1];
    const float* b_enc   = (const float*)d_in[2];
    const float* W_dec   = (const float*)d_in[3];
    const float* b_dec   = (const float*)d_in[4];
    const float* v_e     = (const float*)d_in[5];
    const float* b_e     = (const float*)d_in[6];
    const float* emb     = (const float*)d_in[7];
    const float* W_ih    = (const float*)d_in[8];
    const float* W_hh    = (const float*)d_in[9];
    const float* b_ih    = (const float*)d_in[10];
    const float* b_hh    = (const float*)d_in[11];
    const float* W_out   = (const float*)d_in[12];
    const float* b_out   = (const float*)d_in[13];

    float* ws    = (float*)d_ws;
    float* we    = ws + OFF_WE;
    float* Wgr   = ws + OFF_WGR;
    float* bgr   = ws + OFF_BGR;
    float* WoutT = ws + OFF_WOUTT;
    float* h     = ws + OFF_H;
    float* hT    = ws + OFF_HT;
    float* c     = ws + OFF_C;
    float* wdec  = ws + OFF_WDEC;
    float* sc    = ws + OFF_SC;
    float* Xcat  = ws + OFF_XCAT;

    float* logp_out  = (float*)d_out;
    float* preds_out = logp_out + (size_t)BS * TMAX * VOCAB;
    float* attn_out  = preds_out + (size_t)BS * TMAX;

    {
        long n = (long)G4 * KCAT + G4 + (long)DEC * VOCAB;
        k_prep<<<(int)((n + 255) / 256), 256, 0, stream>>>(W_ih, W_hh, b_ih, b_hh, W_out, Wgr, bgr, WoutT);
    }
    {
        long n = (long)BS * DEC + (long)BS * KCAT;
        k_init<<<(int)((n + 255) / 256), 256, 0, stream>>>(emb, h, hT, c, Xcat);
    }
    k_wenc<<<dim3(8, 8, 128), 256, 0, stream>>>(W_enc, b_enc, enc_out, we);

    for (int t = 0; t < TMAX; t++) {
        k_wdec<<<128, 256, 0, stream>>>(W_dec, b_dec, hT, wdec);
        k_scores<<<512, 256, 0, stream>>>(we, wdec, v_e, b_e, sc);
        k_smctx<<<512, 256, 0, stream>>>(sc, enc_out, attn_out, Xcat, t);
        k_gates_cell<<<dim3(64, 4), 256, 0, stream>>>(Wgr, bgr, Xcat, h, hT, c);
        k_out<<<128, 128, 0, stream>>>(WoutT, b_out, h, emb, logp_out, preds_out, Xcat, t);
    }
}

// Round 5
// 37292.371 us; speedup vs baseline: 1.2962x; 1.1952x over previous
//
#include <hip/hip_runtime.h>
#include <math.h>

#define BS 128
#define L 512
#define ENC 512
#define DEC 1024
#define ATTN 512
#define EMB 256
#define VOCAB 128
#define TMAX 128
#define KCAT 1792  // EMB+ENC+DEC
#define G4 4096    // 4*DEC

// ---- workspace layout (float offsets) ----
#define OFF_WE     0ull                       // [BS][ATTN][L]   33554432
#define OFF_WGR    33554432ull                // [G4][KCAT] d-major  7340032
#define OFF_BGR    40894464ull                // [G4] d-major         4096
#define OFF_WOUTT  40898560ull                // [DEC][VOCAB]       131072
#define OFF_WDT    41029632ull                // [DEC][ATTN] W_dec^T 524288
#define OFF_H      41553920ull                // [BS][DEC]          131072
#define OFF_C      41684992ull                // [BS][DEC]          131072
#define OFF_WDEC   41816064ull                // [BS][ATTN]          65536
#define OFF_SC     41881600ull                // [BS][L]             65536
#define OFF_XCAT   41947136ull                // [BS][KCAT]         229376
// end: 42176512 floats = 168.7 MB

// branch-free tanh: exp + Newton-refined rcp, ~3e-7 rel err, no libm branches
__device__ __forceinline__ float tanh_fast(float x) {
    float ax = fabsf(x);
    float e = __expf(-2.f * ax);          // in (0,1], no overflow
    float d = 1.f + e;
    float r = __builtin_amdgcn_rcpf(d);
    r = r * (2.f - d * r);                // Newton -> ~1 ulp 1/d
    float t = 1.f - 2.f * e * r;          // tanh(|x|)
    return copysignf(t, x);
}

// ---------------- one-time prep: d-major W_gate concat, bias sum, W_out^T, W_dec^T ----------------
__global__ void k_prep(const float* __restrict__ W_ih, const float* __restrict__ W_hh,
                       const float* __restrict__ b_ih, const float* __restrict__ b_hh,
                       const float* __restrict__ W_out, const float* __restrict__ W_dec,
                       float* __restrict__ Wgr, float* __restrict__ bgr,
                       float* __restrict__ WoutT, float* __restrict__ WdT) {
    long i = (long)blockIdx.x * 256 + threadIdx.x;
    if (i < (long)G4 * KCAT) {
        int mp = (int)(i / KCAT), k = (int)(i % KCAT);
        int d = mp >> 2, g = mp & 3;
        int r = g * DEC + d;  // original gate-major row
        Wgr[i] = (k < EMB + ENC) ? W_ih[(long)r * (EMB + ENC) + k]
                                 : W_hh[(long)r * DEC + (k - (EMB + ENC))];
        return;
    }
    long j = i - (long)G4 * KCAT;
    if (j < G4) {
        int d = (int)(j >> 2), g = (int)(j & 3);
        int r = g * DEC + d;
        bgr[j] = b_ih[r] + b_hh[r];
        return;
    }
    long m = j - G4;
    if (m < (long)DEC * VOCAB) {
        int k = (int)(m / VOCAB), v = (int)(m % VOCAB);
        WoutT[m] = W_out[(long)v * DEC + k];
        return;
    }
    long p = m - (long)DEC * VOCAB;
    if (p < (long)DEC * ATTN) {
        int k = (int)(p / ATTN), a = (int)(p % ATTN);
        WdT[p] = W_dec[(long)a * DEC + k];
    }
}

// ---------------- one-time init: h=c=0, Xcat=[emb(SOS)|0|0], wdec=b_dec ----------------
__global__ void k_init(const float* __restrict__ emb_table, const float* __restrict__ b_dec,
                       float* __restrict__ h, float* __restrict__ c,
                       float* __restrict__ Xcat, float* __restrict__ wdec) {
    long i = (long)blockIdx.x * 256 + threadIdx.x;
    if (i < BS * DEC) { h[i] = 0.f; c[i] = 0.f; return; }
    long j = i - BS * DEC;
    if (j < (long)BS * KCAT) {
        int cdx = (int)(j % KCAT);
        Xcat[j] = (cdx < EMB) ? emb_table[cdx] : 0.f;  // SOS = row 0
        return;
    }
    long p = j - (long)BS * KCAT;
    if (p < (long)BS * ATTN) {
        wdec[p] = b_dec[(int)(p % ATTN)];              // h0 = 0
    }
}

// ---------------- weighted_enc[b,a,l] = sum_e W_enc[a,e]*enc[b,e,l] + b_enc[a] ----------------
__global__ __launch_bounds__(256) void k_wenc(const float* __restrict__ W_enc,
                                              const float* __restrict__ b_enc,
                                              const float* __restrict__ enc_out,
                                              float* __restrict__ we) {
    __shared__ float As[16][68];
    __shared__ float Bs[16][68];
    int b = blockIdx.z;
    int a0 = blockIdx.y * 64;
    int l0 = blockIdx.x * 64;
    int t = threadIdx.x;
    int ty = t >> 4, tx = t & 15;
    float acc[4][4] = {};
    for (int e0 = 0; e0 < ENC; e0 += 16) {
        {
            int ar = t >> 2;
            int kg = (t & 3) << 2;
            float4 w4 = *(const float4*)&W_enc[(size_t)(a0 + ar) * ENC + e0 + kg];
            As[kg + 0][ar] = w4.x; As[kg + 1][ar] = w4.y; As[kg + 2][ar] = w4.z; As[kg + 3][ar] = w4.w;
            int er = t >> 4;
            int lg = (t & 15) << 2;
            float4 x4 = *(const float4*)&enc_out[((size_t)b * ENC + e0 + er) * L + l0 + lg];
            *(float4*)&Bs[er][lg] = x4;
        }
        __syncthreads();
        #pragma unroll
        for (int kk = 0; kk < 16; kk++) {
            float4 a4 = *(const float4*)&As[kk][ty * 4];
            float4 x4 = *(const float4*)&Bs[kk][tx * 4];
            float av[4] = {a4.x, a4.y, a4.z, a4.w};
            float xv[4] = {x4.x, x4.y, x4.z, x4.w};
            #pragma unroll
            for (int i = 0; i < 4; i++)
                #pragma unroll
                for (int j = 0; j < 4; j++) acc[i][j] += av[i] * xv[j];
        }
        __syncthreads();
    }
    #pragma unroll
    for (int i = 0; i < 4; i++) {
        float be = b_enc[a0 + ty * 4 + i];
        float4 o = {acc[i][0] + be, acc[i][1] + be, acc[i][2] + be, acc[i][3] + be};
        *(float4*)&we[((size_t)b * ATTN + a0 + ty * 4 + i) * L + l0 + tx * 4] = o;
    }
}

// ---------------- scores[b,l] = sum_a v_e[a]*tanh(we[b,a,l]+wdec[b,a]) + b_e ----------------
__global__ __launch_bounds__(256) void k_scores(const float* __restrict__ we,
                                                const float* __restrict__ wdec,
                                                const float* __restrict__ v_e,
                                                const float* __restrict__ b_e,
                                                float* __restrict__ scores) {
    __shared__ float wd[ATTN];
    __shared__ float ve[ATTN];
    __shared__ float red[128];
    int b = blockIdx.x >> 2;
    int l0 = (blockIdx.x & 3) * 128;
    int t = threadIdx.x;
    wd[t] = wdec[(size_t)b * ATTN + t];
    wd[t + 256] = wdec[(size_t)b * ATTN + t + 256];
    ve[t] = v_e[t];
    ve[t + 256] = v_e[t + 256];
    __syncthreads();
    int l = l0 + (t & 127);
    int ah = t >> 7;
    const float* p = we + ((size_t)b * ATTN + ah * 256) * L + l;
    float acc = 0.f;
    #pragma unroll 8
    for (int a = 0; a < 256; a++) {
        float x = p[(size_t)a * L] + wd[ah * 256 + a];
        acc += ve[ah * 256 + a] * tanh_fast(x);
    }
    if (ah == 1) red[t & 127] = acc;
    __syncthreads();
    if (ah == 0) scores[(size_t)b * L + l] = acc + red[t] + b_e[0];
}

// ---------------- fused softmax + vectorized context ----------------
__global__ __launch_bounds__(256) void k_smctx(const float* __restrict__ scores,
                                               const float* __restrict__ enc_out,
                                               float* __restrict__ attn_out,
                                               float* __restrict__ Xcat, int t_step) {
    __shared__ float al[L];
    __shared__ float red[256];
    int b = blockIdx.x >> 2, ec = blockIdx.x & 3;
    int t = threadIdx.x;
    float v0 = scores[(size_t)b * L + t], v1 = scores[(size_t)b * L + t + 256];
    red[t] = fmaxf(v0, v1);
    __syncthreads();
    for (int s = 128; s; s >>= 1) { if (t < s) red[t] = fmaxf(red[t], red[t + s]); __syncthreads(); }
    float m = red[0];
    __syncthreads();
    float e0 = expf(v0 - m), e1 = expf(v1 - m);
    red[t] = e0 + e1;
    __syncthreads();
    for (int s = 128; s; s >>= 1) { if (t < s) red[t] += red[t + s]; __syncthreads(); }
    float inv = 1.f / red[0];
    al[t] = e0 * inv; al[t + 256] = e1 * inv;
    __syncthreads();
    if (ec == 0) {
        float* dst = attn_out + ((size_t)b * TMAX + t_step) * L;
        dst[t] = al[t]; dst[t + 256] = al[t + 256];
    }
    // context for e in [ec*128, ec*128+128): thread-pair per e, float4 loads
    int w = t >> 6, lane = t & 63;
    int e = ec * 128 + w * 32 + (lane >> 1);
    int lh = (lane & 1) * 256;
    const float* ep = enc_out + ((size_t)b * ENC + e) * L + lh;
    float acc = 0.f;
    #pragma unroll 8
    for (int i = 0; i < 64; i++) {
        float4 x = *(const float4*)&ep[i * 4];
        float4 a4 = *(const float4*)&al[lh + i * 4];
        acc += x.x * a4.x + x.y * a4.y + x.z * a4.z + x.w * a4.w;
    }
    acc += __shfl_xor(acc, 1, 64);
    if ((lane & 1) == 0) Xcat[(size_t)b * KCAT + EMB + e] = acc;
}

// ---------------- gates GEMM (d-major) + LSTM cell ----------------
__global__ __launch_bounds__(256) void k_gates_cell(const float* __restrict__ Wgr,
                                                    const float* __restrict__ bgr,
                                                    const float* __restrict__ Xcat,
                                                    float* __restrict__ h,
                                                    float* __restrict__ c) {
    __shared__ float As[16][68];  // [k][m'] 64 rows
    __shared__ float Xs[16][36];  // [k][b]  32 cols
    int d0 = blockIdx.x * 16;
    int b0 = blockIdx.y * 32;
    int t = threadIdx.x, ty = t >> 4, tx = t & 15;
    float accA[4][2] = {};
    float accB[4][2] = {};
    for (int k0 = 0; k0 < KCAT; k0 += 16) {
        int r = t >> 2, kg = (t & 3) << 2;
        float4 w4 = *(const float4*)&Wgr[(size_t)(d0 * 4 + r) * KCAT + k0 + kg];
        As[kg + 0][r] = w4.x; As[kg + 1][r] = w4.y; As[kg + 2][r] = w4.z; As[kg + 3][r] = w4.w;
        if (t < 128) {
            int br = t >> 2;
            float4 x4 = *(const float4*)&Xcat[(size_t)(b0 + br) * KCAT + k0 + kg];
            Xs[kg + 0][br] = x4.x; Xs[kg + 1][br] = x4.y; Xs[kg + 2][br] = x4.z; Xs[kg + 3][br] = x4.w;
        }
        __syncthreads();
        if (k0 < 896) {
            #pragma unroll
            for (int kk = 0; kk < 16; kk++) {
                float4 a4 = *(const float4*)&As[kk][ty * 4];
                float xb0 = Xs[kk][tx * 2], xb1 = Xs[kk][tx * 2 + 1];
                accA[0][0] += a4.x * xb0; accA[0][1] += a4.x * xb1;
                accA[1][0] += a4.y * xb0; accA[1][1] += a4.y * xb1;
                accA[2][0] += a4.z * xb0; accA[2][1] += a4.z * xb1;
                accA[3][0] += a4.w * xb0; accA[3][1] += a4.w * xb1;
            }
        } else {
            #pragma unroll
            for (int kk = 0; kk < 16; kk++) {
                float4 a4 = *(const float4*)&As[kk][ty * 4];
                float xb0 = Xs[kk][tx * 2], xb1 = Xs[kk][tx * 2 + 1];
                accB[0][0] += a4.x * xb0; accB[0][1] += a4.x * xb1;
                accB[1][0] += a4.y * xb0; accB[1][1] += a4.y * xb1;
                accB[2][0] += a4.z * xb0; accB[2][1] += a4.z * xb1;
                accB[3][0] += a4.w * xb0; accB[3][1] += a4.w * xb1;
            }
        }
        __syncthreads();
    }
    int d = d0 + ty;
    float4 bb = *(const float4*)&bgr[(size_t)d * 4];
    #pragma unroll
    for (int j = 0; j < 2; j++) {
        int b = b0 + tx * 2 + j;
        float gi = accA[0][j] + accB[0][j] + bb.x;
        float gf = accA[1][j] + accB[1][j] + bb.y;
        float gg = accA[2][j] + accB[2][j] + bb.z;
        float go = accA[3][j] + accB[3][j] + bb.w;
        float fi = 1.f / (1.f + expf(-gi));
        float ff = 1.f / (1.f + expf(-gf));
        float fg = tanhf(gg);
        float fo = 1.f / (1.f + expf(-go));
        size_t ix = (size_t)b * DEC + d;
        float cn = ff * c[ix] + fi * fg;
        float hn = fo * tanhf(cn);
        c[ix] = cn;
        h[ix] = hn;
    }
}

// ---------------- logits -> log_softmax -> argmax -> emb + h -> Xcat, wdec(next) ----------------
__global__ __launch_bounds__(256) void k_out(const float* __restrict__ WoutT,
                                             const float* __restrict__ b_out,
                                             const float* __restrict__ h,
                                             const float* __restrict__ emb_table,
                                             const float* __restrict__ WdT,
                                             const float* __restrict__ b_dec,
                                             float* __restrict__ logp_out,
                                             float* __restrict__ preds_out,
                                             float* __restrict__ Xcat,
                                             float* __restrict__ wdec, int t_step) {
    __shared__ float hs[DEC];
    __shared__ float red[256];
    __shared__ float rv[128];
    __shared__ int ri[128];
    int b = blockIdx.x;
    int t = threadIdx.x;
    hs[t] = h[(size_t)b * DEC + t];
    hs[t + 256] = h[(size_t)b * DEC + t + 256];
    hs[t + 512] = h[(size_t)b * DEC + t + 512];
    hs[t + 768] = h[(size_t)b * DEC + t + 768];
    __syncthreads();
    int v = t & 127, kh = t >> 7;
    const float* wp = WoutT + (size_t)kh * 512 * VOCAB + v;
    float acc = 0.f;
    #pragma unroll 8
    for (int k = 0; k < 512; k++) acc += wp[(size_t)k * VOCAB] * hs[kh * 512 + k];
    red[t] = acc;
    __syncthreads();
    float logits = 0.f;
    if (t < 128) {
        logits = red[t] + red[t + 128] + b_out[t];
        rv[t] = logits; ri[t] = t;
    }
    __syncthreads();
    for (int s = 64; s; s >>= 1) {
        if (t < s) {
            float ov = rv[t + s]; int oi = ri[t + s];
            if (ov > rv[t] || (ov == rv[t] && oi < ri[t])) { rv[t] = ov; ri[t] = oi; }
        }
        __syncthreads();
    }
    float m = rv[0]; int am = ri[0];
    __syncthreads();
    if (t < 128) red[t] = expf(logits - m);
    __syncthreads();
    for (int s = 64; s; s >>= 1) { if (t < s && t + s < 128) red[t] += red[t + s]; __syncthreads(); }
    if (t < 128) logp_out[((size_t)b * TMAX + t_step) * VOCAB + t] = logits - m - logf(red[0]);
    if (t == 0) preds_out[(size_t)b * TMAX + t_step] = (float)am;
    // next-step embedding (t < 256 == EMB)
    Xcat[(size_t)b * KCAT + t] = emb_table[(size_t)am * EMB + t];
    // h -> Xcat h-part for next step's gates GEMM
    #pragma unroll
    for (int k = t; k < DEC; k += 256)
        Xcat[(size_t)b * KCAT + EMB + ENC + k] = hs[k];
    // wdec for next step: wdec[b][a] = sum_k hs[k] * WdT[k][a] + b_dec[a]
    #pragma unroll
    for (int a2 = 0; a2 < 2; a2++) {
        int a = t + a2 * 256;
        const float* wdp = WdT + a;
        float s = 0.f;
        #pragma unroll 8
        for (int k = 0; k < DEC; k++) s += wdp[(size_t)k * ATTN] * hs[k];
        wdec[(size_t)b * ATTN + a] = s + b_dec[a];
    }
}

extern "C" void kernel_launch(void* const* d_in, const int* in_sizes, int n_in,
                              void* d_out, int out_size, void* d_ws, size_t ws_size,
                              hipStream_t stream) {
    const float* enc_out = (const float*)d_in[0];
    const float* W_enc   = (const float*)d_in[1];
    const float* b_enc   = (const float*)d_in[2];
    const float* W_dec   = (const float*)d_in[3];
    const float* b_dec   = (const float*)d_in[4];
    const float* v_e     = (const float*)d_in[5];
    const float* b_e     = (const float*)d_in[6];
    const float* emb     = (const float*)d_in[7];
    const float* W_ih    = (const float*)d_in[8];
    const float* W_hh    = (const float*)d_in[9];
    const float* b_ih    = (const float*)d_in[10];
    const float* b_hh    = (const float*)d_in[11];
    const float* W_out   = (const float*)d_in[12];
    const float* b_out   = (const float*)d_in[13];

    float* ws    = (float*)d_ws;
    float* we    = ws + OFF_WE;
    float* Wgr   = ws + OFF_WGR;
    float* bgr   = ws + OFF_BGR;
    float* WoutT = ws + OFF_WOUTT;
    float* WdT   = ws + OFF_WDT;
    float* h     = ws + OFF_H;
    float* c     = ws + OFF_C;
    float* wdec  = ws + OFF_WDEC;
    float* sc    = ws + OFF_SC;
    float* Xcat  = ws + OFF_XCAT;

    float* logp_out  = (float*)d_out;
    float* preds_out = logp_out + (size_t)BS * TMAX * VOCAB;
    float* attn_out  = preds_out + (size_t)BS * TMAX;

    {
        long n = (long)G4 * KCAT + G4 + (long)DEC * VOCAB + (long)DEC * ATTN;
        k_prep<<<(int)((n + 255) / 256), 256, 0, stream>>>(W_ih, W_hh, b_ih, b_hh, W_out, W_dec,
                                                           Wgr, bgr, WoutT, WdT);
    }
    {
        long n = (long)BS * DEC + (long)BS * KCAT + (long)BS * ATTN;
        k_init<<<(int)((n + 255) / 256), 256, 0, stream>>>(emb, b_dec, h, c, Xcat, wdec);
    }
    k_wenc<<<dim3(8, 8, 128), 256, 0, stream>>>(W_enc, b_enc, enc_out, we);

    for (int t = 0; t < TMAX; t++) {
        k_scores<<<512, 256, 0, stream>>>(we, wdec, v_e, b_e, sc);
        k_smctx<<<512, 256, 0, stream>>>(sc, enc_out, attn_out, Xcat, t);
        k_gates_cell<<<dim3(64, 4), 256, 0, stream>>>(Wgr, bgr, Xcat, h, c);
        k_out<<<128, 256, 0, stream>>>(WoutT, b_out, h, emb, WdT, b_dec,
                                       logp_out, preds_out, Xcat, wdec, t);
    }
}

// Round 6
// 25405.276 us; speedup vs baseline: 1.9028x; 1.4679x over previous
//
#include <hip/hip_runtime.h>
#include <math.h>

#define BS 128
#define L 512
#define ENC 512
#define DEC 1024
#define ATTN 512
#define EMB 256
#define VOCAB 128
#define TMAX 128
#define KCAT 1792  // EMB+ENC+DEC
#define G4 4096    // 4*DEC

// ---- workspace layout (float offsets) ----
#define OFF_WE     0ull                       // [BS][ATTN][L]     33554432
#define OFF_WGR    33554432ull                // [G4][KCAT] d-major 7340032
#define OFF_BGR    40894464ull                // [G4] d-major          4096
#define OFF_WOUTT  40898560ull                // [DEC][VOCAB]        131072
#define OFF_WDT    41029632ull                // [DEC][ATTN]         524288
#define OFF_C      41553920ull                // [BS][DEC]           131072
#define OFF_WDEC   41684992ull                // [BS][ATTN]           65536
#define OFF_SC     41750528ull                // [BS][L]              65536
#define OFF_XCAT   41816064ull                // [BS][KCAT]          229376
#define OFF_GPART  42045440ull                // [4][BS][G4]        2097152
// end: 44142592 floats = 176.6 MB

// branch-free tanh: exp + Newton-refined rcp, ~3e-7 rel err, no libm branches
__device__ __forceinline__ float tanh_fast(float x) {
    float ax = fabsf(x);
    float e = __expf(-2.f * ax);          // in (0,1], no overflow
    float d = 1.f + e;
    float r = __builtin_amdgcn_rcpf(d);
    r = r * (2.f - d * r);                // Newton -> ~1 ulp 1/d
    float t = 1.f - 2.f * e * r;          // tanh(|x|)
    return copysignf(t, x);
}

// ---------------- one-time prep: d-major W_gate concat, bias sum, W_out^T, W_dec^T ----------------
__global__ void k_prep(const float* __restrict__ W_ih, const float* __restrict__ W_hh,
                       const float* __restrict__ b_ih, const float* __restrict__ b_hh,
                       const float* __restrict__ W_out, const float* __restrict__ W_dec,
                       float* __restrict__ Wgr, float* __restrict__ bgr,
                       float* __restrict__ WoutT, float* __restrict__ WdT) {
    long i = (long)blockIdx.x * 256 + threadIdx.x;
    if (i < (long)G4 * KCAT) {
        int mp = (int)(i / KCAT), k = (int)(i % KCAT);
        int d = mp >> 2, g = mp & 3;
        int r = g * DEC + d;  // original gate-major row
        Wgr[i] = (k < EMB + ENC) ? W_ih[(long)r * (EMB + ENC) + k]
                                 : W_hh[(long)r * DEC + (k - (EMB + ENC))];
        return;
    }
    long j = i - (long)G4 * KCAT;
    if (j < G4) {
        int d = (int)(j >> 2), g = (int)(j & 3);
        int r = g * DEC + d;
        bgr[j] = b_ih[r] + b_hh[r];
        return;
    }
    long m = j - G4;
    if (m < (long)DEC * VOCAB) {
        int k = (int)(m / VOCAB), v = (int)(m % VOCAB);
        WoutT[m] = W_out[(long)v * DEC + k];
        return;
    }
    long p = m - (long)DEC * VOCAB;
    if (p < (long)DEC * ATTN) {
        int k = (int)(p / ATTN), a = (int)(p % ATTN);
        WdT[p] = W_dec[(long)a * DEC + k];
    }
}

// ---------------- one-time init: c=0, Xcat=[emb(SOS)|0|0], wdec=b_dec ----------------
__global__ void k_init(const float* __restrict__ emb_table, const float* __restrict__ b_dec,
                       float* __restrict__ c, float* __restrict__ Xcat,
                       float* __restrict__ wdec) {
    long i = (long)blockIdx.x * 256 + threadIdx.x;
    if (i < BS * DEC) { c[i] = 0.f; return; }
    long j = i - BS * DEC;
    if (j < (long)BS * KCAT) {
        int cdx = (int)(j % KCAT);
        Xcat[j] = (cdx < EMB) ? emb_table[cdx] : 0.f;  // SOS = row 0
        return;
    }
    long p = j - (long)BS * KCAT;
    if (p < (long)BS * ATTN) {
        wdec[p] = b_dec[(int)(p % ATTN)];              // h0 = 0
    }
}

// ---------------- weighted_enc[b,a,l] = sum_e W_enc[a,e]*enc[b,e,l] + b_enc[a] ----------------
__global__ __launch_bounds__(256) void k_wenc(const float* __restrict__ W_enc,
                                              const float* __restrict__ b_enc,
                                              const float* __restrict__ enc_out,
                                              float* __restrict__ we) {
    __shared__ float As[16][68];
    __shared__ float Bs[16][68];
    int b = blockIdx.z;
    int a0 = blockIdx.y * 64;
    int l0 = blockIdx.x * 64;
    int t = threadIdx.x;
    int ty = t >> 4, tx = t & 15;
    float acc[4][4] = {};
    for (int e0 = 0; e0 < ENC; e0 += 16) {
        {
            int ar = t >> 2;
            int kg = (t & 3) << 2;
            float4 w4 = *(const float4*)&W_enc[(size_t)(a0 + ar) * ENC + e0 + kg];
            As[kg + 0][ar] = w4.x; As[kg + 1][ar] = w4.y; As[kg + 2][ar] = w4.z; As[kg + 3][ar] = w4.w;
            int er = t >> 4;
            int lg = (t & 15) << 2;
            float4 x4 = *(const float4*)&enc_out[((size_t)b * ENC + e0 + er) * L + l0 + lg];
            *(float4*)&Bs[er][lg] = x4;
        }
        __syncthreads();
        #pragma unroll
        for (int kk = 0; kk < 16; kk++) {
            float4 a4 = *(const float4*)&As[kk][ty * 4];
            float4 x4 = *(const float4*)&Bs[kk][tx * 4];
            float av[4] = {a4.x, a4.y, a4.z, a4.w};
            float xv[4] = {x4.x, x4.y, x4.z, x4.w};
            #pragma unroll
            for (int i = 0; i < 4; i++)
                #pragma unroll
                for (int j = 0; j < 4; j++) acc[i][j] += av[i] * xv[j];
        }
        __syncthreads();
    }
    #pragma unroll
    for (int i = 0; i < 4; i++) {
        float be = b_enc[a0 + ty * 4 + i];
        float4 o = {acc[i][0] + be, acc[i][1] + be, acc[i][2] + be, acc[i][3] + be};
        *(float4*)&we[((size_t)b * ATTN + a0 + ty * 4 + i) * L + l0 + tx * 4] = o;
    }
}

// ---------------- scores[b,l] = sum_a v_e[a]*tanh(we[b,a,l]+wdec[b,a]) + b_e ----------------
// grid 1024 = 128 b x 8 l-chunks of 64; 4 a-quarters per block
__global__ __launch_bounds__(256) void k_scores(const float* __restrict__ we,
                                                const float* __restrict__ wdec,
                                                const float* __restrict__ v_e,
                                                const float* __restrict__ b_e,
                                                float* __restrict__ scores) {
    __shared__ float wd[ATTN];
    __shared__ float ve[ATTN];
    __shared__ float red[256];
    int b = blockIdx.x >> 3;
    int l0 = (blockIdx.x & 7) * 64;
    int t = threadIdx.x;
    wd[t] = wdec[(size_t)b * ATTN + t];
    wd[t + 256] = wdec[(size_t)b * ATTN + t + 256];
    ve[t] = v_e[t];
    ve[t + 256] = v_e[t + 256];
    __syncthreads();
    int l = l0 + (t & 63);
    int ah = t >> 6;  // 0..3, a-quarter of 128
    const float* p = we + ((size_t)b * ATTN + ah * 128) * L + l;
    float acc = 0.f;
    #pragma unroll 8
    for (int a = 0; a < 128; a++) {
        float x = p[(size_t)a * L] + wd[ah * 128 + a];
        acc += ve[ah * 128 + a] * tanh_fast(x);
    }
    red[t] = acc;
    __syncthreads();
    if (ah == 0)
        scores[(size_t)b * L + l] = red[t] + red[t + 64] + red[t + 128] + red[t + 192] + b_e[0];
}

// ---------------- fused softmax + vectorized context ----------------
// grid 1024 = 128 b x 8 e-chunks of 64; 4 lanes per e
__global__ __launch_bounds__(256) void k_smctx(const float* __restrict__ scores,
                                               const float* __restrict__ enc_out,
                                               float* __restrict__ attn_out,
                                               float* __restrict__ Xcat, int t_step) {
    __shared__ float al[L];
    __shared__ float red[256];
    int b = blockIdx.x >> 3, ec = blockIdx.x & 7;
    int t = threadIdx.x;
    float v0 = scores[(size_t)b * L + t], v1 = scores[(size_t)b * L + t + 256];
    red[t] = fmaxf(v0, v1);
    __syncthreads();
    for (int s = 128; s; s >>= 1) { if (t < s) red[t] = fmaxf(red[t], red[t + s]); __syncthreads(); }
    float m = red[0];
    __syncthreads();
    float e0 = expf(v0 - m), e1 = expf(v1 - m);
    red[t] = e0 + e1;
    __syncthreads();
    for (int s = 128; s; s >>= 1) { if (t < s) red[t] += red[t + s]; __syncthreads(); }
    float inv = 1.f / red[0];
    al[t] = e0 * inv; al[t + 256] = e1 * inv;
    __syncthreads();
    if (ec == 0) {
        float* dst = attn_out + ((size_t)b * TMAX + t_step) * L;
        dst[t] = al[t]; dst[t + 256] = al[t + 256];
    }
    // context: 4 lanes per e, each covers a 128-float quarter row
    int w = t >> 6, lane = t & 63;
    int e = ec * 64 + w * 16 + (lane >> 2);
    int lh = (lane & 3) * 128;
    const float* ep = enc_out + ((size_t)b * ENC + e) * L + lh;
    float acc = 0.f;
    #pragma unroll 8
    for (int i = 0; i < 32; i++) {
        float4 x = *(const float4*)&ep[i * 4];
        float4 a4 = *(const float4*)&al[lh + i * 4];
        acc += x.x * a4.x + x.y * a4.y + x.z * a4.z + x.w * a4.w;
    }
    acc += __shfl_xor(acc, 1, 64);
    acc += __shfl_xor(acc, 2, 64);
    if ((lane & 3) == 0) Xcat[(size_t)b * KCAT + EMB + e] = acc;
}

// ---------------- gates GEMM partials, K-split x4, b-split x2, reg-prefetched ----------------
// grid (64, 2, 4): 64 m'-rows x 64 b x 448 K per block -> gates_part[ks][b][m']
__global__ __launch_bounds__(256) void k_gates(const float* __restrict__ Wgr,
                                               const float* __restrict__ Xcat,
                                               float* __restrict__ gates_part) {
    __shared__ float As[16][68];  // [k][m'] 64 rows
    __shared__ float Xs[16][68];  // [k][b]  64 cols
    int M0 = blockIdx.x * 64;
    int b0 = blockIdx.y * 64;
    int ks = blockIdx.z;
    int kbase = ks * 448, kend = kbase + 448;
    int t = threadIdx.x, ty = t >> 4, tx = t & 15;
    int r = t >> 2, kg = (t & 3) << 2;
    float acc[4][4] = {};
    // prologue: load first tile into regs
    float4 wreg = *(const float4*)&Wgr[(size_t)(M0 + r) * KCAT + kbase + kg];
    float4 xreg = *(const float4*)&Xcat[(size_t)(b0 + r) * KCAT + kbase + kg];
    for (int k0 = kbase; k0 < kend; k0 += 16) {
        As[kg + 0][r] = wreg.x; As[kg + 1][r] = wreg.y; As[kg + 2][r] = wreg.z; As[kg + 3][r] = wreg.w;
        Xs[kg + 0][r] = xreg.x; Xs[kg + 1][r] = xreg.y; Xs[kg + 2][r] = xreg.z; Xs[kg + 3][r] = xreg.w;
        __syncthreads();
        if (k0 + 16 < kend) {  // prefetch next tile while computing this one
            wreg = *(const float4*)&Wgr[(size_t)(M0 + r) * KCAT + k0 + 16 + kg];
            xreg = *(const float4*)&Xcat[(size_t)(b0 + r) * KCAT + k0 + 16 + kg];
        }
        #pragma unroll
        for (int kk = 0; kk < 16; kk++) {
            float4 a4 = *(const float4*)&As[kk][ty * 4];
            float4 x4 = *(const float4*)&Xs[kk][tx * 4];
            float av[4] = {a4.x, a4.y, a4.z, a4.w};
            float xv[4] = {x4.x, x4.y, x4.z, x4.w};
            #pragma unroll
            for (int i = 0; i < 4; i++)
                #pragma unroll
                for (int j = 0; j < 4; j++) acc[i][j] += av[i] * xv[j];
        }
        __syncthreads();
    }
    float* gp = gates_part + (size_t)ks * BS * G4;
    #pragma unroll
    for (int j = 0; j < 4; j++) {
        float4 o = {acc[0][j], acc[1][j], acc[2][j], acc[3][j]};
        *(float4*)&gp[(size_t)(b0 + tx * 4 + j) * G4 + M0 + ty * 4] = o;
    }
}

// ---------------- cell (sum partials + activations) + logits + argmax + emb + wdec ----------------
__global__ __launch_bounds__(256) void k_out_cell(const float* __restrict__ gates_part,
                                                  const float* __restrict__ bgr,
                                                  const float* __restrict__ WoutT,
                                                  const float* __restrict__ b_out,
                                                  const float* __restrict__ emb_table,
                                                  const float* __restrict__ WdT,
                                                  const float* __restrict__ b_dec,
                                                  float* __restrict__ c,
                                                  float* __restrict__ logp_out,
                                                  float* __restrict__ preds_out,
                                                  float* __restrict__ Xcat,
                                                  float* __restrict__ wdec, int t_step) {
    __shared__ float hs[DEC];
    __shared__ float red[256];
    __shared__ float rv[128];
    __shared__ int ri[128];
    int b = blockIdx.x;
    int t = threadIdx.x;
    // ---- LSTM cell: sum 4 K-partials + bias, activations ----
    #pragma unroll
    for (int q = 0; q < 4; q++) {
        int d = q * 256 + t;
        const float* gp = gates_part + (size_t)b * G4 + d * 4;
        float4 g = *(const float4*)gp;
        #pragma unroll
        for (int ks = 1; ks < 4; ks++) {
            float4 p = *(const float4*)(gp + (size_t)ks * BS * G4);
            g.x += p.x; g.y += p.y; g.z += p.z; g.w += p.w;
        }
        float4 bb = *(const float4*)&bgr[(size_t)d * 4];
        float gi = g.x + bb.x, gf = g.y + bb.y, gg = g.z + bb.z, go = g.w + bb.w;
        float fi = 1.f / (1.f + expf(-gi));
        float ff = 1.f / (1.f + expf(-gf));
        float fg = tanhf(gg);
        float fo = 1.f / (1.f + expf(-go));
        size_t ix = (size_t)b * DEC + d;
        float cn = ff * c[ix] + fi * fg;
        float hn = fo * tanhf(cn);
        c[ix] = cn;
        hs[d] = hn;
        Xcat[(size_t)b * KCAT + EMB + ENC + d] = hn;
    }
    __syncthreads();
    // ---- logits ----
    int v = t & 127, kh = t >> 7;
    const float* wp = WoutT + (size_t)kh * 512 * VOCAB + v;
    float acc = 0.f;
    #pragma unroll 8
    for (int k = 0; k < 512; k++) acc += wp[(size_t)k * VOCAB] * hs[kh * 512 + k];
    red[t] = acc;
    __syncthreads();
    float logits = 0.f;
    if (t < 128) {
        logits = red[t] + red[t + 128] + b_out[t];
        rv[t] = logits; ri[t] = t;
    }
    __syncthreads();
    for (int s = 64; s; s >>= 1) {
        if (t < s) {
            float ov = rv[t + s]; int oi = ri[t + s];
            if (ov > rv[t] || (ov == rv[t] && oi < ri[t])) { rv[t] = ov; ri[t] = oi; }
        }
        __syncthreads();
    }
    float m = rv[0]; int am = ri[0];
    __syncthreads();
    if (t < 128) red[t] = expf(logits - m);
    __syncthreads();
    for (int s = 64; s; s >>= 1) { if (t < s && t + s < 128) red[t] += red[t + s]; __syncthreads(); }
    if (t < 128) logp_out[((size_t)b * TMAX + t_step) * VOCAB + t] = logits - m - logf(red[0]);
    if (t == 0) preds_out[(size_t)b * TMAX + t_step] = (float)am;
    // next-step embedding (t < 256 == EMB)
    Xcat[(size_t)b * KCAT + t] = emb_table[(size_t)am * EMB + t];
    // wdec for next step: wdec[b][a] = sum_k hs[k] * WdT[k][a] + b_dec[a]
    #pragma unroll
    for (int a2 = 0; a2 < 2; a2++) {
        int a = t + a2 * 256;
        const float* wdp = WdT + a;
        float s = 0.f;
        #pragma unroll 8
        for (int k = 0; k < DEC; k++) s += wdp[(size_t)k * ATTN] * hs[k];
        wdec[(size_t)b * ATTN + a] = s + b_dec[a];
    }
}

extern "C" void kernel_launch(void* const* d_in, const int* in_sizes, int n_in,
                              void* d_out, int out_size, void* d_ws, size_t ws_size,
                              hipStream_t stream) {
    const float* enc_out = (const float*)d_in[0];
    const float* W_enc   = (const float*)d_in[1];
    const float* b_enc   = (const float*)d_in[2];
    const float* W_dec   = (const float*)d_in[3];
    const float* b_dec   = (const float*)d_in[4];
    const float* v_e     = (const float*)d_in[5];
    const float* b_e     = (const float*)d_in[6];
    const float* emb     = (const float*)d_in[7];
    const float* W_ih    = (const float*)d_in[8];
    const float* W_hh    = (const float*)d_in[9];
    const float* b_ih    = (const float*)d_in[10];
    const float* b_hh    = (const float*)d_in[11];
    const float* W_out   = (const float*)d_in[12];
    const float* b_out   = (const float*)d_in[13];

    float* ws    = (float*)d_ws;
    float* we    = ws + OFF_WE;
    float* Wgr   = ws + OFF_WGR;
    float* bgr   = ws + OFF_BGR;
    float* WoutT = ws + OFF_WOUTT;
    float* WdT   = ws + OFF_WDT;
    float* c     = ws + OFF_C;
    float* wdec  = ws + OFF_WDEC;
    float* sc    = ws + OFF_SC;
    float* Xcat  = ws + OFF_XCAT;
    float* gpart = ws + OFF_GPART;

    float* logp_out  = (float*)d_out;
    float* preds_out = logp_out + (size_t)BS * TMAX * VOCAB;
    float* attn_out  = preds_out + (size_t)BS * TMAX;

    {
        long n = (long)G4 * KCAT + G4 + (long)DEC * VOCAB + (long)DEC * ATTN;
        k_prep<<<(int)((n + 255) / 256), 256, 0, stream>>>(W_ih, W_hh, b_ih, b_hh, W_out, W_dec,
                                                           Wgr, bgr, WoutT, WdT);
    }
    {
        long n = (long)BS * DEC + (long)BS * KCAT + (long)BS * ATTN;
        k_init<<<(int)((n + 255) / 256), 256, 0, stream>>>(emb, b_dec, c, Xcat, wdec);
    }
    k_wenc<<<dim3(8, 8, 128), 256, 0, stream>>>(W_enc, b_enc, enc_out, we);

    for (int t = 0; t < TMAX; t++) {
        k_scores<<<1024, 256, 0, stream>>>(we, wdec, v_e, b_e, sc);
        k_smctx<<<1024, 256, 0, stream>>>(sc, enc_out, attn_out, Xcat, t);
        k_gates<<<dim3(64, 2, 4), 256, 0, stream>>>(Wgr, Xcat, gpart);
        k_out_cell<<<128, 256, 0, stream>>>(gpart, bgr, WoutT, b_out, emb, WdT, b_dec,
                                            c, logp_out, preds_out, Xcat, wdec, t);
    }
}